// Round 1
// baseline (526.567 us; speedup 1.0000x reference)
//
#include <hip/hip_runtime.h>
#include <math.h>

#define BN 16
#define NA 16384   // anchors per image (128*128), == 1<<14
#define NG 60
#define NC 80
#define ND 85

__device__ __forceinline__ float softplusf(float x){
  // matches jax.nn.softplus: max(x,0) + log1p(exp(-|x|))
  return log1pf(expf(-fabsf(x))) + fmaxf(x, 0.0f);
}

// ---------------- K1: per-anchor prep ----------------
// block = 256 threads, handles 64 anchors. grid = BN * NA/64 = 4096
__global__ __launch_bounds__(256) void k_prep(const float* __restrict__ preds,
    const int* __restrict__ gt_labels, float4* __restrict__ bx,
    float* __restrict__ spsum, float* __restrict__ objp, float* __restrict__ clsg)
{
  __shared__ float4 tilev[64*ND/4];   // 64 rows x 85 floats = 1360 float4
  __shared__ int lab[NG];
  __shared__ float psum[256];
  float* tile = (float*)tilev;
  const int t = threadIdx.x;
  const int blk = blockIdx.x;
  const int b = blk >> 8;                  // 256 blocks per image
  const int n0 = (blk & 255) << 6;         // anchor base
  const float4* srcv = (const float4*)(preds + ((size_t)b*3*NA + n0)*ND); // 16B aligned
  for (int i = t; i < 1360; i += 256) tilev[i] = srcv[i];
  if (t < NG) lab[t] = gt_labels[b*NG + t];
  __syncthreads();
  const int a = t & 63, q = t >> 6;        // anchor-in-tile, quarter (=wave)
  float p = 0.f;
  #pragma unroll
  for (int c = 0; c < 20; c++) p += softplusf(tile[a*ND + 5 + q*20 + c]);
  psum[t] = p;
  __syncthreads();
  const size_t nb = (size_t)b*NA + n0;
  if (t < 64){
    float sp = psum[t] + psum[64+t] + psum[128+t] + psum[192+t];
    spsum[nb + t] = sp;
    bx[nb + t] = make_float4(tile[t*ND+0], tile[t*ND+1], tile[t*ND+2], tile[t*ND+3]);
    objp[nb + t] = tile[t*ND+4];
  }
  // gather label columns: wave q handles 15 gts; coalesced 64-lane writes
  #pragma unroll
  for (int r = 0; r < 15; r++){
    int g = q*15 + r;
    clsg[(((size_t)b*NG + g) << 14) + n0 + a] = tile[a*ND + 5 + lab[g]];
  }
}

// ---------------- K2: per-(image,gt) dynamic-k selection ----------------
// grid = 960 (bid = g*16 + b so an image's blocks share an XCD), block = 256
__global__ __launch_bounds__(256) void k_select(const float* __restrict__ gt_boxes,
    const float4* __restrict__ bx, const float* __restrict__ spsum,
    const float* __restrict__ clsg, int* __restrict__ matched, int* __restrict__ cnt)
{
  const int bid = blockIdx.x;
  const int g = bid >> 4, b = bid & 15;
  const int t = threadIdx.x;
  const int lane = t & 63, w = t >> 6;
  const float* gtp = gt_boxes + (b*NG + g)*4;
  const float gx1 = gtp[0], gy1 = gtp[1], gx2 = gtp[2], gy2 = gtp[3];
  const float garea = fmaxf(gx2-gx1,0.f)*fmaxf(gy2-gy1,0.f);
  const size_t nb = (size_t)b*NA;
  const float* clsrow = clsg + (((size_t)b*NG + g) << 14);

  float il[10];            // top-10 ious, sorted desc
  float cl[10]; int ci[10];// bottom-10 (cost, anchor), sorted asc lex
  #pragma unroll
  for (int j=0;j<10;j++){ il[j] = -1.f; cl[j] = INFINITY; ci[j] = 0x7fffffff; }

  for (int i = t; i < NA; i += 256){
    float4 bb = bx[nb + i];
    float parea = fmaxf(bb.z-bb.x,0.f)*fmaxf(bb.w-bb.y,0.f);
    float ix = fmaxf(fminf(gx2,bb.z)-fmaxf(gx1,bb.x), 0.f);
    float iy = fmaxf(fminf(gy2,bb.w)-fmaxf(gy1,bb.y), 0.f);
    float inter = ix*iy;
    float iou = inter/(garea + parea - inter + 1e-8f);
    float cost = spsum[nb+i] - clsrow[i] + 3.0f*(-logf(iou + 1e-8f));
    if (__any(iou > il[9])){
      float v = iou;
      #pragma unroll
      for (int j=0;j<10;j++){ bool c = v > il[j]; float o = il[j]; il[j]=c?v:o; v=c?o:v; }
    }
    if (__any((cost < cl[9]) || (cost == cl[9] && i < ci[9]))){
      float cv = cost; int ca = i;
      #pragma unroll
      for (int j=0;j<10;j++){
        bool c = (cv < cl[j]) || (cv == cl[j] && ca < ci[j]);
        float ov = cl[j]; int oa = ci[j];
        cl[j] = c?cv:ov; ci[j] = c?ca:oa;
        cv = c?ov:cv;    ca = c?oa:ca;
      }
    }
  }

  __shared__ float wv[4]; __shared__ int wa[4]; __shared__ int ww[4];
  __shared__ float bs10; __shared__ int bwin; __shared__ int bk;

  // --- extract top-10 iou sum ---
  float s10 = 0.f;
  for (int r = 0; r < 10; r++){
    float v = il[0]; int who = t;
    #pragma unroll
    for (int off = 32; off; off >>= 1){
      float ov = __shfl_xor(v, off);
      int   ow = __shfl_xor(who, off);
      if (ov > v || (ov == v && ow < who)){ v = ov; who = ow; }
    }
    if (lane == 0){ wv[w] = v; ww[w] = who; }
    __syncthreads();
    if (t == 0){
      float bv = wv[0]; int bw = ww[0];
      for (int u=1; u<4; u++) if (wv[u] > bv || (wv[u]==bv && ww[u]<bw)){ bv=wv[u]; bw=ww[u]; }
      s10 += bv; bwin = bw;
    }
    __syncthreads();
    if (t == bwin){
      #pragma unroll
      for (int j=0;j<9;j++) il[j] = il[j+1];
      il[9] = -1.f;
    }
    __syncthreads();
  }
  if (t == 0) bk = (int)fmaxf(s10, 1.0f);   // truncation matches astype(int32)
  __syncthreads();
  const int k = bk;

  // --- extract k smallest (cost, anchor) lex pairs; these ARE the matches ---
  for (int r = 0; r < k; r++){
    float v = cl[0]; int a = ci[0]; int who = t;
    #pragma unroll
    for (int off = 32; off; off >>= 1){
      float ov = __shfl_xor(v, off);
      int   oa = __shfl_xor(a, off);
      int   ow = __shfl_xor(who, off);
      if (ov < v || (ov == v && (oa < a || (oa == a && ow < who)))){ v=ov; a=oa; who=ow; }
    }
    if (lane == 0){ wv[w] = v; wa[w] = a; ww[w] = who; }
    __syncthreads();
    if (t == 0){
      float bv = wv[0]; int ba = wa[0]; int bw = ww[0];
      for (int u=1; u<4; u++) if (wv[u] < bv || (wv[u]==bv && wa[u] < ba)){ bv=wv[u]; ba=wa[u]; bw=ww[u]; }
      matched[bid*10 + r] = ba; bwin = bw;
    }
    __syncthreads();
    if (t == bwin){
      #pragma unroll
      for (int j=0;j<9;j++){ cl[j] = cl[j+1]; ci[j] = ci[j+1]; }
      cl[9] = INFINITY; ci[9] = 0x7fffffff;
    }
    __syncthreads();
  }
  if (t == 0) cnt[bid] = k;
}

// ---------------- K3: per-image loss over candidate anchors ----------------
__device__ __forceinline__ float blockSum(float v, float* red, int t){
  red[t] = v; __syncthreads();
  #pragma unroll
  for (int s = 128; s > 0; s >>= 1){
    if (t < s) red[t] += red[t+s];
    __syncthreads();
  }
  float r = red[0]; __syncthreads();
  return r;
}

__global__ __launch_bounds__(256) void k_loss(const float* __restrict__ gt_boxes,
    const int* __restrict__ matched, const int* __restrict__ cnt,
    const float4* __restrict__ bx, const float* __restrict__ spsum,
    const float* __restrict__ objp, const float* __restrict__ clsg,
    float* __restrict__ partials)
{
  __shared__ int lists[NG*10];
  __shared__ int cnts[NG];
  __shared__ float gtb[NG][4];
  __shared__ float red[256];
  const int b = blockIdx.x;
  const int t = threadIdx.x;
  for (int i = t; i < NG*10; i += 256){
    int g = i/10, j = i - g*10;
    lists[i] = matched[(g*16 + b)*10 + j];
  }
  if (t < NG){
    cnts[t] = cnt[t*16 + b];
    float4 gg = ((const float4*)gt_boxes)[b*NG + t];
    gtb[t][0]=gg.x; gtb[t][1]=gg.y; gtb[t][2]=gg.z; gtb[t][3]=gg.w;
  }
  __syncthreads();
  for (int i = t; i < NG*10; i += 256){
    int g = i/10, j = i - g*10;
    if (j >= cnts[g]) lists[i] = -1;   // mask poison/unused entries
  }
  __syncthreads();

  float boxs = 0.f, objs = 0.f, clss = 0.f, nfg = 0.f;
  const size_t nb = (size_t)b*NA;
  for (int s = t; s < NG*10; s += 256){
    int n = lists[s];
    if (n < 0) continue;
    int g = s/10;
    // count gts matching this anchor; find first
    int m = 0, firstg = -1;
    for (int gp = 0; gp < NG; gp++){
      bool mem = false;
      #pragma unroll
      for (int jp = 0; jp < 10; jp++) mem |= (lists[gp*10 + jp] == n);
      if (mem){ m++; if (firstg < 0) firstg = gp; }
    }
    if (g != firstg) continue;        // unique owner slot per anchor
    float4 bb = bx[nb + n];
    float sp = spsum[nb + n];
    int mg = g;
    if (m > 1){
      // best_gt = argmin over ALL gts of cost
      float parea = fmaxf(bb.z-bb.x,0.f)*fmaxf(bb.w-bb.y,0.f);
      float best = INFINITY; int bg = 0;
      for (int gp = 0; gp < NG; gp++){
        float ga = fmaxf(gtb[gp][2]-gtb[gp][0],0.f)*fmaxf(gtb[gp][3]-gtb[gp][1],0.f);
        float ix = fmaxf(fminf(gtb[gp][2],bb.z)-fmaxf(gtb[gp][0],bb.x),0.f);
        float iy = fmaxf(fminf(gtb[gp][3],bb.w)-fmaxf(gtb[gp][1],bb.y),0.f);
        float inter = ix*iy;
        float iou = inter/(ga + parea - inter + 1e-8f);
        float c = sp - clsg[(((size_t)b*NG + gp) << 14) + n] + 3.0f*(-logf(iou + 1e-8f));
        if (c < best){ best = c; bg = gp; }
      }
      bool mem = false;
      #pragma unroll
      for (int jp = 0; jp < 10; jp++) mem |= (lists[bg*10 + jp] == n);
      if (!mem) continue;             // multi & best not in matched set -> not fg
      mg = bg;
    }
    // losses for this fg anchor
    float gx1=gtb[mg][0], gy1=gtb[mg][1], gx2=gtb[mg][2], gy2=gtb[mg][3];
    float d0=bb.x-gx1, d1=bb.y-gy1, d2=bb.z-gx2, d3=bb.w-gy2;
    float a0=fabsf(d0), a1=fabsf(d1), a2=fabsf(d2), a3=fabsf(d3);
    float sl = (a0<1.f ? 0.5f*d0*d0 : a0-0.5f)
             + (a1<1.f ? 0.5f*d1*d1 : a1-0.5f)
             + (a2<1.f ? 0.5f*d2*d2 : a2-0.5f)
             + (a3<1.f ? 0.5f*d3*d3 : a3-0.5f);
    float parea = fmaxf(bb.z-bb.x,0.f)*fmaxf(bb.w-bb.y,0.f);
    float garea = fmaxf(gx2-gx1,0.f)*fmaxf(gy2-gy1,0.f);
    float ix = fmaxf(fminf(gx2,bb.z)-fmaxf(gx1,bb.x),0.f);
    float iy = fmaxf(fminf(gy2,bb.w)-fmaxf(gy1,bb.y),0.f);
    float inter = ix*iy;
    float iou_t = inter/(parea + garea - inter + 1e-8f);
    float ob = objp[nb + n];
    float sg = 1.f/(1.f + expf(-ob));
    float obce = softplusf(sg) - sg*iou_t;
    float clsb = sp - clsg[(((size_t)b*NG + mg) << 14) + n];
    boxs += sl; objs += obce; clss += clsb; nfg += 1.f;
  }
  float tb = blockSum(boxs, red, t);
  float to = blockSum(objs, red, t);
  float tc = blockSum(clss, red, t);
  float tn = blockSum(nfg,  red, t);
  if (t == 0){
    partials[b*4+0] = tb; partials[b*4+1] = to;
    partials[b*4+2] = tc; partials[b*4+3] = tn;
  }
}

// ---------------- K4: final combine ----------------
__global__ void k_final(const float* __restrict__ partials, float* __restrict__ out){
  if (threadIdx.x == 0 && blockIdx.x == 0){
    float tb=0.f, to=0.f, tc=0.f;
    for (int b = 0; b < BN; b++){
      float nf = fmaxf(partials[b*4+3], 1.f);
      tb += partials[b*4+0] / (nf * 4.f);
      to += partials[b*4+1] / nf;
      tc += partials[b*4+2] / (nf * (float)NC);
    }
    out[0] = (5.f*tb + to + tc) / (float)BN;
    out[1] = tb / (float)BN;
    out[2] = to / (float)BN;
    out[3] = tc / (float)BN;
  }
}

extern "C" void kernel_launch(void* const* d_in, const int* in_sizes, int n_in,
                              void* d_out, int out_size, void* d_ws, size_t ws_size,
                              hipStream_t stream)
{
  (void)in_sizes; (void)n_in; (void)out_size; (void)ws_size;
  const float* preds     = (const float*)d_in[0];
  const float* gt_boxes  = (const float*)d_in[1];
  const int*   gt_labels = (const int*)d_in[2];
  float* out = (float*)d_out;

  char* ws = (char*)d_ws;
  float4* bx    = (float4*)ws;                                  // BN*NA float4  (4 MB)
  float*  spsum = (float*)(ws + (size_t)BN*NA*sizeof(float4));  // BN*NA         (1 MB)
  float*  objp  = spsum + (size_t)BN*NA;                        // BN*NA         (1 MB)
  float*  clsg  = objp  + (size_t)BN*NA;                        // BN*NG*NA      (60 MB)
  int* matched  = (int*)(clsg + (size_t)BN*NG*NA);              // BN*NG*10
  int* cnt      = matched + BN*NG*10;                           // BN*NG
  float* partials = (float*)(cnt + BN*NG);                      // BN*4

  k_prep  <<<BN*NA/64, 256, 0, stream>>>(preds, gt_labels, bx, spsum, objp, clsg);
  k_select<<<BN*NG,    256, 0, stream>>>(gt_boxes, bx, spsum, clsg, matched, cnt);
  k_loss  <<<BN,       256, 0, stream>>>(gt_boxes, matched, cnt, bx, spsum, objp, clsg, partials);
  k_final <<<1, 64, 0, stream>>>(partials, out);
}

// Round 4
// 498.367 us; speedup vs baseline: 1.0566x; 1.0566x over previous
//
#include <hip/hip_runtime.h>
#include <math.h>

#define BN 16
#define NA 16384   // anchors per image (128*128)
#define NG 60
#define NC 80
#define ND 85
#define SLABS 16   // slabs per image
#define SLAB 1024  // anchors per slab
#define TILE 128   // anchors per LDS tile
#define NTILES 8   // SLAB/TILE
#define GSLOT 64   // padded gt slots

__device__ __forceinline__ float softplus_fast(float x){
  // softplus(x) = max(x,0) + log1p(exp(-|x|)); u=exp(-|x|) >= 6.7e-3 for |x|<=5,
  // so log(1+u) via v_log is accurate to ~1e-7 abs — far inside the 5.3 threshold.
  return __logf(1.0f + __expf(-fabsf(x))) + fmaxf(x, 0.0f);
}

// ---------------- F1: fused prep + per-(image,gt) scan ----------------
// grid = 256 (b = blk>>4, slab = blk&15), block = 1024 (16 waves)
// thread t: g = t>>4 (64 gt slots, 60 real), strip = t&15; scans 64 anchors.
__global__ __launch_bounds__(1024) void f_scan(
    const float* __restrict__ preds, const float* __restrict__ gt_boxes,
    const int* __restrict__ gt_labels, float* __restrict__ mlist)
{
  __shared__ float4 tilev[TILE*ND/4];   // 128 rows x 85 floats = 43520 B
  __shared__ float sp[TILE];
  __shared__ float4 gtb4[GSLOT];
  __shared__ float gar[GSLOT];
  __shared__ int   lab[GSLOT];
  float* tile = (float*)tilev;
  const int t = threadIdx.x;
  const int b = blockIdx.x >> 4;
  const int slab = blockIdx.x & 15;

  if (t < GSLOT){
    float4 gg = make_float4(0.f,0.f,0.f,0.f);
    int lb = 0;
    if (t < NG){ gg = ((const float4*)gt_boxes)[b*NG + t]; lb = gt_labels[b*NG + t]; }
    gtb4[t] = gg; lab[t] = lb;
    gar[t] = fmaxf(gg.z-gg.x,0.f)*fmaxf(gg.w-gg.y,0.f);
  }
  __syncthreads();
  const int g = t >> 4, strip = t & 15;
  const float4 gt = gtb4[g];
  const float ga = gar[g];
  const int lg = lab[g];

  float il[10], cl[10]; int ci[10];
  #pragma unroll
  for (int j=0;j<10;j++){ il[j] = -1.f; cl[j] = INFINITY; ci[j] = 0x7fffffff; }

  const float4* src0 = (const float4*)(preds + ((size_t)b*3*NA + (size_t)slab*SLAB)*ND);

  for (int ti = 0; ti < NTILES; ti++){
    __syncthreads();                       // protect tile/sp from previous iter readers
    const float4* src = src0 + (size_t)ti*(TILE*ND/4);
    #pragma unroll
    for (int i = 0; i < 3; i++){
      int idx = t + i*1024;
      if (idx < TILE*ND/4) tilev[idx] = src[idx];
    }
    __syncthreads();
    // spsum: 8 threads per anchor, 10 softplus each, shfl-tree combine
    {
      int a = t >> 3, part = t & 7;
      const float* rowc = tile + a*ND + 5 + part*10;
      float p = 0.f;
      #pragma unroll
      for (int c = 0; c < 10; c++) p += softplus_fast(rowc[c]);
      p += __shfl_xor(p, 1);
      p += __shfl_xor(p, 2);
      p += __shfl_xor(p, 4);
      if (part == 0) sp[a] = p;
    }
    __syncthreads();
    const int n0 = slab*SLAB + ti*TILE;
    for (int r = 0; r < 8; r++){
      int a = (r<<4) + strip;
      const float* row = tile + a*ND;
      float bx1=row[0], by1=row[1], bx2=row[2], by2=row[3];
      float clsv = row[5+lg];
      float spv  = sp[a];
      float pa = fmaxf(bx2-bx1,0.f)*fmaxf(by2-by1,0.f);
      float ix = fmaxf(fminf(gt.z,bx2)-fmaxf(gt.x,bx1),0.f);
      float iy = fmaxf(fminf(gt.w,by2)-fmaxf(gt.y,by1),0.f);
      float inter = ix*iy;
      float iou = inter/(ga + pa - inter + 1e-8f);
      float cost = fmaf(-3.0f, __logf(iou + 1e-8f), spv - clsv);
      int idx = n0 + a;
      if (__any(iou > il[9])){            // on this data most ious are 0 -> skips
        float v = iou;
        #pragma unroll
        for (int j=0;j<10;j++){ bool c = v > il[j]; float o=il[j]; il[j]=c?v:o; v=c?o:v; }
      }
      { // strict < keeps first-seen on ties; scan order = ascending idx => stable
        float cv = cost; int ca = idx;
        #pragma unroll
        for (int j=0;j<10;j++){
          bool c = cv < cl[j];
          float ov=cl[j]; int oa=ci[j];
          cl[j]=c?cv:ov; ci[j]=c?ca:oa;
          cv=c?ov:cv;    ca=c?oa:ca;
        }
      }
    }
  }

  // merge 16 strips per g (16-lane butterflies), write slab-level lists
  float* outp = mlist + (((size_t)(b*SLABS + slab))*NG + g)*30;
  for (int r = 0; r < 10; r++){           // top-10 iou values
    float v = il[0]; int who = strip;
    #pragma unroll
    for (int off = 8; off; off >>= 1){
      float ov = __shfl_xor(v, off, 16);
      int   ow = __shfl_xor(who, off, 16);
      if (ov > v || (ov == v && ow < who)){ v = ov; who = ow; }
    }
    if (strip == r && g < NG) outp[r] = v;
    if (strip == who){
      #pragma unroll
      for (int j=0;j<9;j++) il[j] = il[j+1];
      il[9] = -1.f;
    }
  }
  for (int r = 0; r < 10; r++){           // bottom-10 (cost, idx) lex
    float v = cl[0]; int a = ci[0];
    #pragma unroll
    for (int off = 8; off; off >>= 1){
      float ov = __shfl_xor(v, off, 16);
      int   oa = __shfl_xor(a, off, 16);
      if (ov < v || (ov == v && oa < a)){ v = ov; a = oa; }
    }
    if (strip == r && g < NG){ outp[10+r] = v; outp[20+r] = __int_as_float(a); }
    if (cl[0] == v && ci[0] == a){        // unique owner (idx unique)
      #pragma unroll
      for (int j=0;j<9;j++){ cl[j]=cl[j+1]; ci[j]=ci[j+1]; }
      cl[9] = INFINITY; ci[9] = 0x7fffffff;
    }
  }
}

// ---------------- F2: cross-slab merge + dynamic-k selection ----------------
// grid = 960 (bid = b*60+g), block = 64 (one wave)
__global__ __launch_bounds__(64) void f_merge(const float* __restrict__ mlist,
    int* __restrict__ matched, int* __restrict__ cnt)
{
  __shared__ float buf[SLABS*30];
  const int bid = blockIdx.x;
  const int b = bid / NG, g = bid - b*NG;
  const int t = threadIdx.x;
  for (int i = t; i < SLABS*30; i += 64){
    int slab = i / 30, j = i - slab*30;
    buf[i] = mlist[(((size_t)(b*SLABS + slab))*NG + g)*30 + j];
  }
  __syncthreads();

  // --- top-10 of 160 iou values (3 items/lane) ---
  float v0=-1.f, v1=-1.f, v2=-1.f;
  {
    int q0 = t, q1 = t+64, q2 = t+128;
    v0 = buf[(q0/10)*30 + (q0%10)];
    v1 = buf[(q1/10)*30 + (q1%10)];
    if (q2 < 160) v2 = buf[(q2/10)*30 + (q2%10)];
    if (v1 > v0){ float x=v0; v0=v1; v1=x; }
    if (v2 > v1){ float x=v1; v1=v2; v2=x; }
    if (v1 > v0){ float x=v0; v0=v1; v1=x; }
  }
  float s10 = 0.f;
  for (int r = 0; r < 10; r++){
    float v = v0; int who = t;
    #pragma unroll
    for (int off = 32; off; off >>= 1){
      float ov = __shfl_xor(v, off);
      int   ow = __shfl_xor(who, off);
      if (ov > v || (ov == v && ow < who)){ v = ov; who = ow; }
    }
    s10 += v;
    if (t == who){ v0=v1; v1=v2; v2=-1.f; }
  }
  const int k = (int)fmaxf(s10, 1.0f);

  // --- k smallest of 160 (cost, idx) lex pairs ---
  float c0=INFINITY, c1=INFINITY, c2=INFINITY;
  int   a0=0x7fffffff, a1=0x7fffffff, a2=0x7fffffff;
  {
    int q0 = t, q1 = t+64, q2 = t+128;
    c0 = buf[(q0/10)*30 + 10 + (q0%10)]; a0 = __float_as_int(buf[(q0/10)*30 + 20 + (q0%10)]);
    c1 = buf[(q1/10)*30 + 10 + (q1%10)]; a1 = __float_as_int(buf[(q1/10)*30 + 20 + (q1%10)]);
    if (q2 < 160){ c2 = buf[(q2/10)*30 + 10 + (q2%10)]; a2 = __float_as_int(buf[(q2/10)*30 + 20 + (q2%10)]); }
    if (c1 < c0 || (c1==c0 && a1 < a0)){ float x=c0;c0=c1;c1=x; int y=a0;a0=a1;a1=y; }
    if (c2 < c1 || (c2==c1 && a2 < a1)){ float x=c1;c1=c2;c2=x; int y=a1;a1=a2;a2=y; }
    if (c1 < c0 || (c1==c0 && a1 < a0)){ float x=c0;c0=c1;c1=x; int y=a0;a0=a1;a1=y; }
  }
  for (int r = 0; r < k; r++){
    float v = c0; int a = a0; int who = t;
    #pragma unroll
    for (int off = 32; off; off >>= 1){
      float ov = __shfl_xor(v, off);
      int   oa = __shfl_xor(a, off);
      int   ow = __shfl_xor(who, off);
      if (ov < v || (ov == v && (oa < a || (oa == a && ow < who)))){ v=ov; a=oa; who=ow; }
    }
    if (t == r) matched[bid*10 + r] = a;
    if (t == who){ c0=c1; a0=a1; c1=c2; a1=a2; c2=INFINITY; a2=0x7fffffff; }
  }
  if (t == 0) cnt[bid] = k;
}

// ---------------- F3: per-image loss over candidate anchors ----------------
__device__ __forceinline__ float blockSum(float v, float* red, int t){
  red[t] = v; __syncthreads();
  #pragma unroll
  for (int s = 128; s > 0; s >>= 1){
    if (t < s) red[t] += red[t+s];
    __syncthreads();
  }
  float r = red[0]; __syncthreads();
  return r;
}

__global__ __launch_bounds__(256) void f_loss(const float* __restrict__ preds,
    const float* __restrict__ gt_boxes, const int* __restrict__ gt_labels,
    const int* __restrict__ matched, const int* __restrict__ cnt,
    float* __restrict__ partials)
{
  __shared__ int lists[NG*10];
  __shared__ int cnts[NG];
  __shared__ float gtb[NG][4];
  __shared__ int labs[NG];
  __shared__ float red[256];
  const int b = blockIdx.x;
  const int t = threadIdx.x;
  for (int i = t; i < NG*10; i += 256) lists[i] = matched[b*NG*10 + i];
  if (t < NG){
    cnts[t] = cnt[b*NG + t];
    float4 gg = ((const float4*)gt_boxes)[b*NG + t];
    gtb[t][0]=gg.x; gtb[t][1]=gg.y; gtb[t][2]=gg.z; gtb[t][3]=gg.w;
    labs[t] = gt_labels[b*NG + t];
  }
  __syncthreads();
  for (int i = t; i < NG*10; i += 256){
    int g = i/10, j = i - g*10;
    if (j >= cnts[g]) lists[i] = -1;
  }
  __syncthreads();

  float boxs = 0.f, objs = 0.f, clss = 0.f, nfg = 0.f;
  const float* rowb = preds + (size_t)b*3*NA*ND;
  for (int s = t; s < NG*10; s += 256){
    int n = lists[s];
    if (n < 0) continue;
    int g = s/10;
    int m = 0, firstg = -1;
    for (int gp = 0; gp < NG; gp++){
      bool mem = false;
      #pragma unroll
      for (int jp = 0; jp < 10; jp++) mem |= (lists[gp*10 + jp] == n);
      if (mem){ m++; if (firstg < 0) firstg = gp; }
    }
    if (g != firstg) continue;        // unique owner slot per anchor
    const float* row = rowb + (size_t)n*ND;
    float p0=row[0], p1=row[1], p2=row[2], p3=row[3];
    float obj = row[4];
    float spv = 0.f;
    for (int c = 0; c < NC; c++) spv += softplus_fast(row[5+c]);
    int mg = g;
    float pa = fmaxf(p2-p0,0.f)*fmaxf(p3-p1,0.f);
    if (m > 1){
      float best = INFINITY; int bg = 0;
      for (int gp = 0; gp < NG; gp++){
        float ga = fmaxf(gtb[gp][2]-gtb[gp][0],0.f)*fmaxf(gtb[gp][3]-gtb[gp][1],0.f);
        float ix = fmaxf(fminf(gtb[gp][2],p2)-fmaxf(gtb[gp][0],p0),0.f);
        float iy = fmaxf(fminf(gtb[gp][3],p3)-fmaxf(gtb[gp][1],p1),0.f);
        float inter = ix*iy;
        float iou = inter/(ga + pa - inter + 1e-8f);
        float c = fmaf(-3.0f, __logf(iou + 1e-8f), spv - row[5+labs[gp]]);
        if (c < best){ best = c; bg = gp; }
      }
      bool mem = false;
      #pragma unroll
      for (int jp = 0; jp < 10; jp++) mem |= (lists[bg*10 + jp] == n);
      if (!mem) continue;             // multi & best not in matched set -> not fg
      mg = bg;
    }
    float gx1=gtb[mg][0], gy1=gtb[mg][1], gx2=gtb[mg][2], gy2=gtb[mg][3];
    float d0=p0-gx1, d1=p1-gy1, d2=p2-gx2, d3=p3-gy2;
    float q0=fabsf(d0), q1=fabsf(d1), q2=fabsf(d2), q3=fabsf(d3);
    float sl = (q0<1.f ? 0.5f*d0*d0 : q0-0.5f)
             + (q1<1.f ? 0.5f*d1*d1 : q1-0.5f)
             + (q2<1.f ? 0.5f*d2*d2 : q2-0.5f)
             + (q3<1.f ? 0.5f*d3*d3 : q3-0.5f);
    float ga = fmaxf(gx2-gx1,0.f)*fmaxf(gy2-gy1,0.f);
    float ix = fmaxf(fminf(gx2,p2)-fmaxf(gx1,p0),0.f);
    float iy = fmaxf(fminf(gy2,p3)-fmaxf(gy1,p1),0.f);
    float inter = ix*iy;
    float iou_t = inter/(pa + ga - inter + 1e-8f);
    float sg = 1.f/(1.f + __expf(-obj));
    float obce = softplus_fast(sg) - sg*iou_t;
    float clsb = spv - row[5+labs[mg]];
    boxs += sl; objs += obce; clss += clsb; nfg += 1.f;
  }
  float tb = blockSum(boxs, red, t);
  float to = blockSum(objs, red, t);
  float tc = blockSum(clss, red, t);
  float tn = blockSum(nfg,  red, t);
  if (t == 0){
    partials[b*4+0] = tb; partials[b*4+1] = to;
    partials[b*4+2] = tc; partials[b*4+3] = tn;
  }
}

// ---------------- F4: final combine ----------------
__global__ void f_final(const float* __restrict__ partials, float* __restrict__ out){
  if (threadIdx.x == 0 && blockIdx.x == 0){
    float tb=0.f, to=0.f, tc=0.f;
    for (int b = 0; b < BN; b++){
      float nf = fmaxf(partials[b*4+3], 1.f);
      tb += partials[b*4+0] / (nf * 4.f);
      to += partials[b*4+1] / nf;
      tc += partials[b*4+2] / (nf * (float)NC);
    }
    out[0] = (5.f*tb + to + tc) / (float)BN;
    out[1] = tb / (float)BN;
    out[2] = to / (float)BN;
    out[3] = tc / (float)BN;
  }
}

extern "C" void kernel_launch(void* const* d_in, const int* in_sizes, int n_in,
                              void* d_out, int out_size, void* d_ws, size_t ws_size,
                              hipStream_t stream)
{
  (void)in_sizes; (void)n_in; (void)out_size; (void)ws_size;
  const float* preds     = (const float*)d_in[0];
  const float* gt_boxes  = (const float*)d_in[1];
  const int*   gt_labels = (const int*)d_in[2];
  float* out = (float*)d_out;

  float* mlist  = (float*)d_ws;                       // 16*16*60*30 floats (1.84 MB)
  int* matched  = (int*)(mlist + (size_t)BN*SLABS*NG*30); // 16*60*10
  int* cnt      = matched + BN*NG*10;                 // 16*60
  float* partials = (float*)(cnt + BN*NG);            // 16*4

  f_scan <<<BN*SLABS, 1024, 0, stream>>>(preds, gt_boxes, gt_labels, mlist);
  f_merge<<<BN*NG,      64, 0, stream>>>(mlist, matched, cnt);
  f_loss <<<BN,        256, 0, stream>>>(preds, gt_boxes, gt_labels, matched, cnt, partials);
  f_final<<<1,          64, 0, stream>>>(partials, out);
}